// Round 7
// baseline (227.728 us; speedup 1.0000x reference)
//
#include <hip/hip_runtime.h>
#include <hip/hip_bf16.h>
#include <math.h>

#define F 128
#define HID 32
#define NH 4
#define TILE 64

typedef __attribute__((ext_vector_type(8))) short bf16x8;
typedef __attribute__((ext_vector_type(4))) float f32x4;

__device__ __forceinline__ float silu_f(float x) {
    return x / (1.0f + __expf(-x));
}

__device__ __forceinline__ uint f2bf(float f) {  // RNE float->bf16 (low 16 of result)
    union { float f; uint u; } v; v.f = f;
    uint r = v.u + 0x7fffu + ((v.u >> 16) & 1u);
    return r >> 16;
}

// Scatter segment boundaries: starts[b] = first atom index with seg_id >= b.
__global__ void seg_starts_kernel(const int* __restrict__ seg, int* __restrict__ starts,
                                  int N, int B) {
    int i = blockIdx.x * blockDim.x + threadIdx.x;
    if (i >= N) return;
    int id = seg[i];
    if (i == 0) {
        for (int b = 0; b <= id; ++b) starts[b] = 0;
    } else {
        int prev = seg[i - 1];
        for (int b = prev + 1; b <= id; ++b) starts[b] = i;
    }
    if (i == N - 1) {
        for (int b = id + 1; b <= B; ++b) starts[b] = N;
    }
}

// One block (4 waves) per crystal. Software-pipelined over 64-atom tiles:
//   A: issue tile k+1 global loads -> regs          (latency hidden under B..E)
//   B: MFMA MLP on LDS buf[k&1] -> logits sTL
//   C: barrier
//   D: online softmax, wave wv = head wv (own-wave sTW, no barrier after)
//   E: weighted accumulate, wave = head, lane = feat-pair, from buf[k&1]
//   F: convert + ds_write regs -> buf[(k+1)&1]
//   G: barrier
// 2 barriers/tile; stage latency fully overlapped (T14 + double buffer).
__global__ __launch_bounds__(256, 4) void fused4_kernel(
    const float* __restrict__ atom_fea, const int* __restrict__ starts,
    const float* __restrict__ W1, const float* __restrict__ b1,
    const float* __restrict__ W2, const float* __restrict__ b2,
    const float* __restrict__ Wp, const float* __restrict__ bp,
    float* __restrict__ out) {
    __shared__ ushort sFea[2][TILE * F];  // 2 x 16 KB bf16, 16B-chunk XOR swizzle
    __shared__ float sTL[TILE * 5];       // logits [atom][head], stride 5
    __shared__ float sTW[NH * 65];        // exp weights [head][atom]

    const int t = threadIdx.x;
    const int b = blockIdx.x;
    const int start = starts[b];
    const int end = starts[b + 1];
    const int wv = t >> 6;    // wave: MFMA atom-group AND head (softmax + accumulate)
    const int lane = t & 63;
    const int lg = lane >> 4;
    const int l15 = lane & 15;

    // ---- one-time register preloads (layout verified in R6: absmax 9.8e-4) ----
    bf16x8 w1f[2][4];  // A-frags of W1T: [h-tile][k-step]; lane: h'=l15, k'=lg*8+j
    #pragma unroll
    for (int m0 = 0; m0 < 2; ++m0)
        #pragma unroll
        for (int kk = 0; kk < 4; ++kk) {
            bf16x8 fr;
            #pragma unroll
            for (int j = 0; j < 8; ++j)
                fr[j] = (short)f2bf(W1[(kk * 32 + lg * 8 + j) * HID + m0 * 16 + l15]);
            w1f[m0][kk] = fr;
        }
    float b1r[8], w2r[8][4];
    #pragma unroll
    for (int m0 = 0; m0 < 2; ++m0)
        #pragma unroll
        for (int r = 0; r < 4; ++r) {
            const int h = m0 * 16 + lg * 4 + r;
            b1r[m0 * 4 + r] = b1[h];
            #pragma unroll
            for (int j = 0; j < 4; ++j) w2r[m0 * 4 + r][j] = W2[h * NH + j];
        }
    const float b2r0 = b2[0], b2r1 = b2[1], b2r2 = b2[2], b2r3 = b2[3];

    float m_run = -INFINITY, s_run = 0.0f;
    float accC0 = 0.0f, accC1 = 0.0f;  // head wv, feats 2*lane, 2*lane+1

    const int nt = (end > start) ? (end - start + TILE - 1) / TILE : 0;

    // ---- prologue: stage tile 0 into buf0 ----
    if (nt > 0) {
        #pragma unroll
        for (int i = 0; i < 8; ++i) {
            const int q = t + i * 256;  // 0..2047 = 64 rows x 32 float4
            const int r = q >> 5, c4 = q & 31;
            int a = start + r; a = (a < end) ? a : end - 1;  // clamp: defined values
            const float4 v = *((const float4*)(atom_fea + (size_t)a * F) + c4);
            uint2 pk;
            pk.x = (f2bf(v.y) << 16) | f2bf(v.x);
            pk.y = (f2bf(v.w) << 16) | f2bf(v.z);
            *(uint2*)&sFea[0][r * F + ((c4 >> 1) ^ (r & 7)) * 8 + (c4 & 1) * 4] = pk;
        }
    }
    __syncthreads();

    for (int ti = 0; ti < nt; ++ti) {
        const int base = start + ti * TILE;
        const int T = min(TILE, end - base);
        const ushort* fb = sFea[ti & 1];
        const bool has_next = (ti + 1 < nt);  // block-uniform

        // ---- A: prefetch next tile into regs (issue only; consumed at F) ----
        float4 pf[8];
        if (has_next) {
            const int nbase = base + TILE;
            #pragma unroll
            for (int i = 0; i < 8; ++i) {
                const int q = t + i * 256;
                const int r = q >> 5, c4 = q & 31;
                int a = nbase + r; a = (a < end) ? a : end - 1;
                pf[i] = *((const float4*)(atom_fea + (size_t)a * F) + c4);
            }
        }

        // ---- B: MFMA MLP, wave wv owns atoms 16wv..16wv+15 ----
        {
            f32x4 acc0, acc1;
            #pragma unroll
            for (int r = 0; r < 4; ++r) { acc0[r] = b1r[r]; acc1[r] = b1r[4 + r]; }
            const int row = wv * 16 + l15;
            #pragma unroll
            for (int kk = 0; kk < 4; ++kk) {
                const int chunk = (kk * 4 + lg) ^ (row & 7);
                const bf16x8 bf = *(const bf16x8*)&fb[row * F + chunk * 8];
                acc0 = __builtin_amdgcn_mfma_f32_16x16x32_bf16(w1f[0][kk], bf, acc0, 0, 0, 0);
                acc1 = __builtin_amdgcn_mfma_f32_16x16x32_bf16(w1f[1][kk], bf, acc1, 0, 0, 0);
            }
            float p0 = 0, p1 = 0, p2 = 0, p3 = 0;
            #pragma unroll
            for (int r = 0; r < 4; ++r) {
                const float s0 = silu_f(acc0[r]);
                const float s1 = silu_f(acc1[r]);
                p0 = fmaf(s0, w2r[r][0], fmaf(s1, w2r[4 + r][0], p0));
                p1 = fmaf(s0, w2r[r][1], fmaf(s1, w2r[4 + r][1], p1));
                p2 = fmaf(s0, w2r[r][2], fmaf(s1, w2r[4 + r][2], p2));
                p3 = fmaf(s0, w2r[r][3], fmaf(s1, w2r[4 + r][3], p3));
            }
            p0 += __shfl_xor(p0, 16); p0 += __shfl_xor(p0, 32);
            p1 += __shfl_xor(p1, 16); p1 += __shfl_xor(p1, 32);
            p2 += __shfl_xor(p2, 16); p2 += __shfl_xor(p2, 32);
            p3 += __shfl_xor(p3, 16); p3 += __shfl_xor(p3, 32);
            if (lane < 16) {
                float* d = &sTL[(wv * 16 + lane) * 5];
                d[0] = p0 + b2r0; d[1] = p1 + b2r1; d[2] = p2 + b2r2; d[3] = p3 + b2r3;
            }
        }
        __syncthreads();  // C: sTL ready; all MFMA reads of fb done

        // ---- D: online softmax, wave wv = head wv, lane = atom ----
        {
            const float v = (lane < T) ? sTL[lane * 5 + wv] : -INFINITY;
            float mt = v;
            #pragma unroll
            for (int d = 1; d < 64; d <<= 1) mt = fmaxf(mt, __shfl_xor(mt, d));
            const float m_new = fmaxf(m_run, mt);
            const float r = __expf(m_run - m_new);  // first tile: exp(-inf)=0
            const float e = (lane < T) ? __expf(v - m_new) : 0.0f;
            sTW[wv * 65 + lane] = e;  // own-wave region
            float se = e;
            #pragma unroll
            for (int d = 1; d < 64; d <<= 1) se += __shfl_xor(se, d);
            s_run = fmaf(s_run, r, se);
            m_run = m_new;
            accC0 *= r;
            accC1 *= r;
        }

        // ---- E: weighted accumulate, wave = head wv, lane = feat-pair ----
        {
            const float* tw = &sTW[wv * 65];
            const int ccol = lane >> 2;
            const int coff = (lane & 3) * 2;
            int a = 0;
            for (; a + 7 < T; a += 8) {
                uint dd[8]; float ww[8];
                #pragma unroll
                for (int u = 0; u < 8; ++u) {
                    ww[u] = tw[a + u];
                    dd[u] = *(const uint*)&fb[(a + u) * F + ((ccol ^ ((a + u) & 7))) * 8 + coff];
                }
                #pragma unroll
                for (int u = 0; u < 8; ++u) {
                    accC0 = fmaf(ww[u], __uint_as_float(dd[u] << 16), accC0);
                    accC1 = fmaf(ww[u], __uint_as_float(dd[u] & 0xffff0000u), accC1);
                }
            }
            for (; a < T; ++a) {
                const float w = tw[a];
                const uint d = *(const uint*)&fb[a * F + ((ccol ^ (a & 7))) * 8 + coff];
                accC0 = fmaf(w, __uint_as_float(d << 16), accC0);
                accC1 = fmaf(w, __uint_as_float(d & 0xffff0000u), accC1);
            }
        }

        // ---- F: write prefetched tile into alternate buffer ----
        if (has_next) {
            ushort* wb = (ushort*)sFea[(ti + 1) & 1];
            #pragma unroll
            for (int i = 0; i < 8; ++i) {
                const int q = t + i * 256;
                const int r = q >> 5, c4 = q & 31;
                uint2 pk;
                pk.x = (f2bf(pf[i].y) << 16) | f2bf(pf[i].x);
                pk.y = (f2bf(pf[i].w) << 16) | f2bf(pf[i].z);
                *(uint2*)&wb[r * F + ((c4 >> 1) ^ (r & 7)) * 8 + (c4 & 1) * 4] = pk;
            }
        }
        __syncthreads();  // G: buf[(ti+1)&1] staged; fb free for overwrite next+1
    }

    const float inv = (s_run > 0.0f) ? 1.0f / s_run : 0.0f;

    // ---- epilogue: out[b] = silu(wacc @ Wp + bp); alias LDS ----
    float* sWacc = (float*)sFea[0];          // 512 floats, k = h*F + f
    float* sPart = (float*)sFea[0] + 512;    // 256 floats
    sWacc[wv * F + lane * 2] = accC0 * inv;
    sWacc[wv * F + lane * 2 + 1] = accC1 * inv;
    __syncthreads();
    {
        const int f = t & 127, half = t >> 7;
        float sum = 0.0f;
        const float* wp = Wp + (size_t)(half * 256) * F + f;
        const float* wa = &sWacc[half * 256];
        #pragma unroll 8
        for (int k = 0; k < 256; ++k) sum = fmaf(wa[k], wp[(size_t)k * F], sum);
        sPart[t] = sum;
    }
    __syncthreads();
    if (t < 128) out[(size_t)b * F + t] = silu_f(sPart[t] + sPart[t + 128] + bp[t]);
}

extern "C" void kernel_launch(void* const* d_in, const int* in_sizes, int n_in,
                              void* d_out, int out_size, void* d_ws, size_t ws_size,
                              hipStream_t stream) {
    const float* atom_fea = (const float*)d_in[0];
    const int* seg = (const int*)d_in[1];
    const float* W1 = (const float*)d_in[3];
    const float* b1 = (const float*)d_in[4];
    const float* W2 = (const float*)d_in[5];
    const float* b2 = (const float*)d_in[6];
    const float* Wp = (const float*)d_in[7];
    const float* bp = (const float*)d_in[8];
    float* out = (float*)d_out;

    const int N = in_sizes[0] / F;
    const int B = out_size / F;
    int* starts = (int*)d_ws;  // (B+1) ints

    seg_starts_kernel<<<(N + 255) / 256, 256, 0, stream>>>(seg, starts, N, B);
    fused4_kernel<<<B, 256, 0, stream>>>(atom_fea, starts, W1, b1, W2, b2, Wp, bp, out);
}

// Round 8
// 107.110 us; speedup vs baseline: 2.1261x; 2.1261x over previous
//
#include <hip/hip_runtime.h>
#include <hip/hip_bf16.h>
#include <math.h>

#define F 128
#define HID 32
#define NH 4
#define TILE 64

typedef __attribute__((ext_vector_type(8))) short bf16x8;
typedef __attribute__((ext_vector_type(4))) float f32x4;

__device__ __forceinline__ float silu_f(float x) {
    return x / (1.0f + __expf(-x));
}

__device__ __forceinline__ uint f2bf(float f) {  // RNE float->bf16 (low 16 of result)
    union { float f; uint u; } v; v.f = f;
    uint r = v.u + 0x7fffu + ((v.u >> 16) & 1u);
    return r >> 16;
}

// Scatter segment boundaries: starts[b] = first atom index with seg_id >= b.
__global__ void seg_starts_kernel(const int* __restrict__ seg, int* __restrict__ starts,
                                  int N, int B) {
    int i = blockIdx.x * blockDim.x + threadIdx.x;
    if (i >= N) return;
    int id = seg[i];
    if (i == 0) {
        for (int b = 0; b <= id; ++b) starts[b] = 0;
    } else {
        int prev = seg[i - 1];
        for (int b = prev + 1; b <= id; ++b) starts[b] = i;
    }
    if (i == N - 1) {
        for (int b = id + 1; b <= B; ++b) starts[b] = N;
    }
}

// One block (4 waves) per crystal. Software-pipelined over 64-atom tiles:
//   A: issue tile k+1 global loads -> pf regs      (latency hides under B)
//   B: MFMA MLP on LDS buf[k&1] -> logits sTL
//   F: convert + ds_write pf -> buf[(k+1)&1]       (pf live range: A..F only)
//   barrier
//   D: online softmax, wave wv = head wv (own-wave sTW)
//   E: weighted accumulate from buf[k&1]
//   barrier
// launch_bounds(256,2): let pf stay in VGPRs (R7's (256,4) caused a 210 MB
// scratch spill at VGPR=64 -> WRITE_SIZE blowup).
__global__ __launch_bounds__(256, 2) void fused5_kernel(
    const float* __restrict__ atom_fea, const int* __restrict__ starts,
    const float* __restrict__ W1, const float* __restrict__ b1,
    const float* __restrict__ W2, const float* __restrict__ b2,
    const float* __restrict__ Wp, const float* __restrict__ bp,
    float* __restrict__ out) {
    __shared__ ushort sFea[2][TILE * F];  // 2 x 16 KB bf16, 16B-chunk XOR swizzle
    __shared__ float sTL[TILE * 5];       // logits [atom][head], stride 5
    __shared__ float sTW[NH * 65];        // exp weights [head][atom]

    const int t = threadIdx.x;
    const int b = blockIdx.x;
    const int start = starts[b];
    const int end = starts[b + 1];
    const int wv = t >> 6;    // wave: MFMA atom-group AND head (softmax + accumulate)
    const int lane = t & 63;
    const int lg = lane >> 4;
    const int l15 = lane & 15;

    // ---- one-time register preloads (layout verified R6: absmax 9.8e-4) ----
    bf16x8 w1f[2][4];  // A-frags of W1T: [h-tile][k-step]; lane: h'=l15, k'=lg*8+j
    #pragma unroll
    for (int m0 = 0; m0 < 2; ++m0)
        #pragma unroll
        for (int kk = 0; kk < 4; ++kk) {
            bf16x8 fr;
            #pragma unroll
            for (int j = 0; j < 8; ++j)
                fr[j] = (short)f2bf(W1[(kk * 32 + lg * 8 + j) * HID + m0 * 16 + l15]);
            w1f[m0][kk] = fr;
        }
    float b1r[8], w2r[8][4];
    #pragma unroll
    for (int m0 = 0; m0 < 2; ++m0)
        #pragma unroll
        for (int r = 0; r < 4; ++r) {
            const int h = m0 * 16 + lg * 4 + r;
            b1r[m0 * 4 + r] = b1[h];
            #pragma unroll
            for (int j = 0; j < 4; ++j) w2r[m0 * 4 + r][j] = W2[h * NH + j];
        }
    const float b2r0 = b2[0], b2r1 = b2[1], b2r2 = b2[2], b2r3 = b2[3];

    float m_run = -INFINITY, s_run = 0.0f;
    float accC0 = 0.0f, accC1 = 0.0f;  // head wv, feats 2*lane, 2*lane+1

    const int nt = (end > start) ? (end - start + TILE - 1) / TILE : 0;

    // ---- prologue: stage tile 0 into buf0 ----
    if (nt > 0) {
        #pragma unroll
        for (int i = 0; i < 8; ++i) {
            const int q = t + i * 256;  // 0..2047 = 64 rows x 32 float4
            const int r = q >> 5, c4 = q & 31;
            int a = start + r; a = (a < end) ? a : end - 1;  // clamp: defined values
            const float4 v = *((const float4*)(atom_fea + (size_t)a * F) + c4);
            uint2 pk;
            pk.x = (f2bf(v.y) << 16) | f2bf(v.x);
            pk.y = (f2bf(v.w) << 16) | f2bf(v.z);
            *(uint2*)&sFea[0][r * F + ((c4 >> 1) ^ (r & 7)) * 8 + (c4 & 1) * 4] = pk;
        }
    }
    __syncthreads();

    for (int ti = 0; ti < nt; ++ti) {
        const int base = start + ti * TILE;
        const int T = min(TILE, end - base);
        const ushort* fb = sFea[ti & 1];
        const bool has_next = (ti + 1 < nt);  // block-uniform

        // ---- A: prefetch next tile into regs (consumed at F, just below) ----
        float4 pf[8];
        if (has_next) {
            const int nbase = base + TILE;
            #pragma unroll
            for (int i = 0; i < 8; ++i) {
                const int q = t + i * 256;
                const int r = q >> 5, c4 = q & 31;
                int a = nbase + r; a = (a < end) ? a : end - 1;
                pf[i] = *((const float4*)(atom_fea + (size_t)a * F) + c4);
            }
        }

        // ---- B: MFMA MLP, wave wv owns atoms 16wv..16wv+15 ----
        {
            f32x4 acc0, acc1;
            #pragma unroll
            for (int r = 0; r < 4; ++r) { acc0[r] = b1r[r]; acc1[r] = b1r[4 + r]; }
            const int row = wv * 16 + l15;
            #pragma unroll
            for (int kk = 0; kk < 4; ++kk) {
                const int chunk = (kk * 4 + lg) ^ (row & 7);
                const bf16x8 bf = *(const bf16x8*)&fb[row * F + chunk * 8];
                acc0 = __builtin_amdgcn_mfma_f32_16x16x32_bf16(w1f[0][kk], bf, acc0, 0, 0, 0);
                acc1 = __builtin_amdgcn_mfma_f32_16x16x32_bf16(w1f[1][kk], bf, acc1, 0, 0, 0);
            }
            float p0 = 0, p1 = 0, p2 = 0, p3 = 0;
            #pragma unroll
            for (int r = 0; r < 4; ++r) {
                const float s0 = silu_f(acc0[r]);
                const float s1 = silu_f(acc1[r]);
                p0 = fmaf(s0, w2r[r][0], fmaf(s1, w2r[4 + r][0], p0));
                p1 = fmaf(s0, w2r[r][1], fmaf(s1, w2r[4 + r][1], p1));
                p2 = fmaf(s0, w2r[r][2], fmaf(s1, w2r[4 + r][2], p2));
                p3 = fmaf(s0, w2r[r][3], fmaf(s1, w2r[4 + r][3], p3));
            }
            p0 += __shfl_xor(p0, 16); p0 += __shfl_xor(p0, 32);
            p1 += __shfl_xor(p1, 16); p1 += __shfl_xor(p1, 32);
            p2 += __shfl_xor(p2, 16); p2 += __shfl_xor(p2, 32);
            p3 += __shfl_xor(p3, 16); p3 += __shfl_xor(p3, 32);
            if (lane < 16) {
                float* d = &sTL[(wv * 16 + lane) * 5];
                d[0] = p0 + b2r0; d[1] = p1 + b2r1; d[2] = p2 + b2r2; d[3] = p3 + b2r3;
            }
        }

        // ---- F: write prefetched tile into alternate buffer (ends pf liveness;
        //         wb's old readers finished at the previous end-of-tile barrier) ----
        if (has_next) {
            ushort* wb = (ushort*)sFea[(ti + 1) & 1];
            #pragma unroll
            for (int i = 0; i < 8; ++i) {
                const int q = t + i * 256;
                const int r = q >> 5, c4 = q & 31;
                uint2 pk;
                pk.x = (f2bf(pf[i].y) << 16) | f2bf(pf[i].x);
                pk.y = (f2bf(pf[i].w) << 16) | f2bf(pf[i].z);
                *(uint2*)&wb[r * F + ((c4 >> 1) ^ (r & 7)) * 8 + (c4 & 1) * 4] = pk;
            }
        }
        __syncthreads();  // sTL ready (cross-wave); fb MFMA reads done

        // ---- D: online softmax, wave wv = head wv, lane = atom ----
        {
            const float v = (lane < T) ? sTL[lane * 5 + wv] : -INFINITY;
            float mt = v;
            #pragma unroll
            for (int d = 1; d < 64; d <<= 1) mt = fmaxf(mt, __shfl_xor(mt, d));
            const float m_new = fmaxf(m_run, mt);
            const float r = __expf(m_run - m_new);  // first tile: exp(-inf)=0
            const float e = (lane < T) ? __expf(v - m_new) : 0.0f;
            sTW[wv * 65 + lane] = e;  // own-wave region
            float se = e;
            #pragma unroll
            for (int d = 1; d < 64; d <<= 1) se += __shfl_xor(se, d);
            s_run = fmaf(s_run, r, se);
            m_run = m_new;
            accC0 *= r;
            accC1 *= r;
        }

        // ---- E: weighted accumulate, wave = head wv, lane = feat-pair ----
        {
            const float* tw = &sTW[wv * 65];
            const int ccol = lane >> 2;
            const int coff = (lane & 3) * 2;
            int a = 0;
            for (; a + 7 < T; a += 8) {
                uint dd[8]; float ww[8];
                #pragma unroll
                for (int u = 0; u < 8; ++u) {
                    ww[u] = tw[a + u];
                    dd[u] = *(const uint*)&fb[(a + u) * F + ((ccol ^ ((a + u) & 7))) * 8 + coff];
                }
                #pragma unroll
                for (int u = 0; u < 8; ++u) {
                    accC0 = fmaf(ww[u], __uint_as_float(dd[u] << 16), accC0);
                    accC1 = fmaf(ww[u], __uint_as_float(dd[u] & 0xffff0000u), accC1);
                }
            }
            for (; a < T; ++a) {
                const float w = tw[a];
                const uint d = *(const uint*)&fb[a * F + ((ccol ^ (a & 7))) * 8 + coff];
                accC0 = fmaf(w, __uint_as_float(d << 16), accC0);
                accC1 = fmaf(w, __uint_as_float(d & 0xffff0000u), accC1);
            }
        }
        __syncthreads();  // E reads of fb/sTW done; wb fully staged for next B
    }

    const float inv = (s_run > 0.0f) ? 1.0f / s_run : 0.0f;

    // ---- epilogue: out[b] = silu(wacc @ Wp + bp); alias LDS ----
    float* sWacc = (float*)sFea[0];          // 512 floats, k = h*F + f
    float* sPart = (float*)sFea[0] + 512;    // 256 floats
    sWacc[wv * F + lane * 2] = accC0 * inv;
    sWacc[wv * F + lane * 2 + 1] = accC1 * inv;
    __syncthreads();
    {
        const int f = t & 127, half = t >> 7;
        float sum = 0.0f;
        const float* wp = Wp + (size_t)(half * 256) * F + f;
        const float* wa = &sWacc[half * 256];
        #pragma unroll 8
        for (int k = 0; k < 256; ++k) sum = fmaf(wa[k], wp[(size_t)k * F], sum);
        sPart[t] = sum;
    }
    __syncthreads();
    if (t < 128) out[(size_t)b * F + t] = silu_f(sPart[t] + sPart[t + 128] + bp[t]);
}

extern "C" void kernel_launch(void* const* d_in, const int* in_sizes, int n_in,
                              void* d_out, int out_size, void* d_ws, size_t ws_size,
                              hipStream_t stream) {
    const float* atom_fea = (const float*)d_in[0];
    const int* seg = (const int*)d_in[1];
    const float* W1 = (const float*)d_in[3];
    const float* b1 = (const float*)d_in[4];
    const float* W2 = (const float*)d_in[5];
    const float* b2 = (const float*)d_in[6];
    const float* Wp = (const float*)d_in[7];
    const float* bp = (const float*)d_in[8];
    float* out = (float*)d_out;

    const int N = in_sizes[0] / F;
    const int B = out_size / F;
    int* starts = (int*)d_ws;  // (B+1) ints

    seg_starts_kernel<<<(N + 255) / 256, 256, 0, stream>>>(seg, starts, N, B);
    fused5_kernel<<<B, 256, 0, stream>>>(atom_fea, starts, W1, b1, W2, b2, Wp, bp, out);
}

// Round 9
// 81.507 us; speedup vs baseline: 2.7940x; 1.3141x over previous
//
#include <hip/hip_runtime.h>
#include <math.h>

#define F 128
#define HID 32
#define NH 4
#define TILE 64
#define ROWB 512  // bytes per fp32 row (128 * 4)

typedef __attribute__((ext_vector_type(8))) short bf16x8;
typedef __attribute__((ext_vector_type(4))) float f32x4;

__device__ __forceinline__ float silu_f(float x) {
    return x / (1.0f + __expf(-x));
}

__device__ __forceinline__ uint f2bf(float f) {  // RNE float->bf16 (one-time W1 prep)
    union { float f; uint u; } v; v.f = f;
    uint r = v.u + 0x7fffu + ((v.u >> 16) & 1u);
    return r >> 16;
}

__device__ __forceinline__ uint cvtpk_bf16(float lo, float hi) {  // HW RNE pack
    uint r;
    asm("v_cvt_pk_bf16_f32 %0, %1, %2" : "=v"(r) : "v"(lo), "v"(hi));
    return r;
}

__device__ __forceinline__ void gload_lds16(const void* g, void* l) {
    // async 16B global->LDS; LDS dest is wave-uniform base + lane*16
    __builtin_amdgcn_global_load_lds(
        (const __attribute__((address_space(1))) void*)g,
        (__attribute__((address_space(3))) void*)l, 16, 0, 0);
}

// Scatter segment boundaries: starts[b] = first atom index with seg_id >= b.
__global__ void seg_starts_kernel(const int* __restrict__ seg, int* __restrict__ starts,
                                  int N, int B) {
    int i = blockIdx.x * blockDim.x + threadIdx.x;
    if (i >= N) return;
    int id = seg[i];
    if (i == 0) {
        for (int b = 0; b <= id; ++b) starts[b] = 0;
    } else {
        int prev = seg[i - 1];
        for (int b = prev + 1; b <= id; ++b) starts[b] = i;
    }
    if (i == N - 1) {
        for (int b = id + 1; b <= B; ++b) starts[b] = N;
    }
}

// One block (4 waves) per crystal. Per 64-atom tile (fp32 LDS, double-buffered):
//   issue async DMA of tile k+1 (pre-swizzled source, linear LDS dest)
//   B: MFMA MLP on buf[pb] (cvt_pk at read) -> logits sTL        | barrier
//   D: online softmax, wave wv = head wv -> sTW/sR               | barrier
//   C: weighted fp32 accumulate from buf[pb] (wave = atom-quarter)
//   vmcnt(0) drain of the DMA                                    | barrier
// Writes normalized Wacc[b][4][128] to workspace; projection is K4.
__global__ __launch_bounds__(256, 2) void fused6_kernel(
    const float* __restrict__ atom_fea, const int* __restrict__ starts,
    const float* __restrict__ W1, const float* __restrict__ b1,
    const float* __restrict__ W2, const float* __restrict__ b2,
    float* __restrict__ gWacc) {
    __shared__ float sBuf[2][TILE * F];  // 2 x 32 KB fp32, 16B-chunk XOR swizzle
    __shared__ float sTL[TILE * 5];      // logits [atom][head], stride 5
    __shared__ float sTW[NH * 65];       // exp weights [head][atom]
    __shared__ float sR[NH];             // per-tile rescale per head
    __shared__ float sInv[NH];           // final 1/denom per head

    const int t = threadIdx.x;
    const int b = blockIdx.x;
    const int start = starts[b];
    const int end = starts[b + 1];
    const int wv = t >> 6;    // wave: MFMA atom-group, softmax head, phase-C atom-quarter
    const int lane = t & 63;
    const int lg = lane >> 4;
    const int l15 = lane & 15;
    const int ch = lane & 3;          // phase-C head
    const int co = (lane >> 2) & 15;  // phase-C feat-oct

    // ---- per-thread DMA slot constants: slot q holds LDS chunk (r, q&31),
    //      sourced from global chunk (q&31)^(r&7) of row r (inverse swizzle) ----
    int roff[8], coff[8];
    #pragma unroll
    for (int i = 0; i < 8; ++i) {
        const int q = i * 256 + t;
        roff[i] = q >> 5;
        coff[i] = ((q & 31) ^ (roff[i] & 7)) << 4;
    }

    // ---- one-time register preloads (layout verified R6: absmax 9.8e-4) ----
    bf16x8 w1f[2][4];  // A-frags of W1T: [h-tile][k-step]; lane: h'=l15, k'=lg*8+j
    #pragma unroll
    for (int m0 = 0; m0 < 2; ++m0)
        #pragma unroll
        for (int kk = 0; kk < 4; ++kk) {
            bf16x8 fr;
            #pragma unroll
            for (int j = 0; j < 8; ++j)
                fr[j] = (short)f2bf(W1[(kk * 32 + lg * 8 + j) * HID + m0 * 16 + l15]);
            w1f[m0][kk] = fr;
        }
    float b1r[8], w2r[8][4];
    #pragma unroll
    for (int m0 = 0; m0 < 2; ++m0)
        #pragma unroll
        for (int r = 0; r < 4; ++r) {
            const int h = m0 * 16 + lg * 4 + r;
            b1r[m0 * 4 + r] = b1[h];
            #pragma unroll
            for (int j = 0; j < 4; ++j) w2r[m0 * 4 + r][j] = W2[h * NH + j];
        }
    const float b2r0 = b2[0], b2r1 = b2[1], b2r2 = b2[2], b2r3 = b2[3];

    float m_run = -INFINITY, s_run = 0.0f;
    float acc8[8] = {0, 0, 0, 0, 0, 0, 0, 0};  // (head ch, feats 8co..8co+7), own quarter

    const int nt = (end > start) ? (end - start + TILE - 1) / TILE : 0;
    const char* gbase = (const char*)atom_fea;

    // ---- prologue: DMA tile 0 into buf0 ----
    if (nt > 0) {
        #pragma unroll
        for (int i = 0; i < 8; ++i) {
            int a = start + roff[i]; a = (a < end) ? a : end - 1;  // clamp rows
            gload_lds16(gbase + (size_t)a * ROWB + coff[i],
                        (char*)sBuf[0] + i * 4096 + wv * 1024);
        }
    }
    asm volatile("s_waitcnt vmcnt(0)");
    __syncthreads();

    int pb = 0;
    for (int ti = 0; ti < nt; ++ti) {
        const int base = start + ti * TILE;
        const int T = min(TILE, end - base);
        const char* bufc = (const char*)sBuf[pb];
        const bool has_next = (ti + 1 < nt);  // block-uniform

        // ---- issue async DMA of tile k+1 into the alternate buffer ----
        if (has_next) {
            const int nbase = base + TILE;
            char* ldst = (char*)sBuf[pb ^ 1];
            #pragma unroll
            for (int i = 0; i < 8; ++i) {
                int a = nbase + roff[i]; a = (a < end) ? a : end - 1;
                gload_lds16(gbase + (size_t)a * ROWB + coff[i],
                            ldst + i * 4096 + wv * 1024);
            }
        }

        // ---- B: MFMA MLP, wave wv owns atoms 16wv..16wv+15 ----
        {
            f32x4 acc0, acc1;
            #pragma unroll
            for (int r = 0; r < 4; ++r) { acc0[r] = b1r[r]; acc1[r] = b1r[4 + r]; }
            const int row = wv * 16 + l15;
            const char* rb = bufc + row * ROWB;
            const int rs = row & 7;
            #pragma unroll
            for (int kk = 0; kk < 4; ++kk) {
                const int c0 = kk * 8 + lg * 2;
                const float4 va = *(const float4*)(rb + ((c0 ^ rs) << 4));
                const float4 vb = *(const float4*)(rb + (((c0 + 1) ^ rs) << 4));
                union { bf16x8 v; uint u[4]; } fr;
                fr.u[0] = cvtpk_bf16(va.x, va.y);
                fr.u[1] = cvtpk_bf16(va.z, va.w);
                fr.u[2] = cvtpk_bf16(vb.x, vb.y);
                fr.u[3] = cvtpk_bf16(vb.z, vb.w);
                acc0 = __builtin_amdgcn_mfma_f32_16x16x32_bf16(w1f[0][kk], fr.v, acc0, 0, 0, 0);
                acc1 = __builtin_amdgcn_mfma_f32_16x16x32_bf16(w1f[1][kk], fr.v, acc1, 0, 0, 0);
            }
            float p0 = 0, p1 = 0, p2 = 0, p3 = 0;
            #pragma unroll
            for (int r = 0; r < 4; ++r) {
                const float s0 = silu_f(acc0[r]);
                const float s1 = silu_f(acc1[r]);
                p0 = fmaf(s0, w2r[r][0], fmaf(s1, w2r[4 + r][0], p0));
                p1 = fmaf(s0, w2r[r][1], fmaf(s1, w2r[4 + r][1], p1));
                p2 = fmaf(s0, w2r[r][2], fmaf(s1, w2r[4 + r][2], p2));
                p3 = fmaf(s0, w2r[r][3], fmaf(s1, w2r[4 + r][3], p3));
            }
            p0 += __shfl_xor(p0, 16); p0 += __shfl_xor(p0, 32);
            p1 += __shfl_xor(p1, 16); p1 += __shfl_xor(p1, 32);
            p2 += __shfl_xor(p2, 16); p2 += __shfl_xor(p2, 32);
            p3 += __shfl_xor(p3, 16); p3 += __shfl_xor(p3, 32);
            if (lane < 16) {
                float* d = &sTL[(wv * 16 + lane) * 5];
                d[0] = p0 + b2r0; d[1] = p1 + b2r1; d[2] = p2 + b2r2; d[3] = p3 + b2r3;
            }
        }
        __syncthreads();  // #1: sTL visible

        // ---- D: online softmax, wave wv = head wv, lane = atom ----
        {
            const float v = (lane < T) ? sTL[lane * 5 + wv] : -INFINITY;
            float mt = v;
            #pragma unroll
            for (int d = 1; d < 64; d <<= 1) mt = fmaxf(mt, __shfl_xor(mt, d));
            const float m_new = fmaxf(m_run, mt);
            const float r = __expf(m_run - m_new);  // first tile: exp(-inf)=0
            const float e = (lane < T) ? __expf(v - m_new) : 0.0f;
            sTW[wv * 65 + lane] = e;
            float se = e;
            #pragma unroll
            for (int d = 1; d < 64; d <<= 1) se += __shfl_xor(se, d);
            s_run = fmaf(s_run, r, se);
            m_run = m_new;
            if (lane == 0) sR[wv] = r;
        }
        __syncthreads();  // #2: sTW/sR visible cross-wave (fixes R6's latent race)

        // ---- C: fp32 weighted accumulate; wave wv = atoms 16wv..+16,
        //         lane = (head ch, oct co) ----
        {
            const float rr = sR[ch];
            #pragma unroll
            for (int i = 0; i < 8; ++i) acc8[i] *= rr;
            const int abase = wv * 16;
            #pragma unroll 4
            for (int i = 0; i < 16; ++i) {
                const int a = abase + i;
                const float w = sTW[ch * 65 + a];
                const int sw = a & 7;
                const char* ra = bufc + a * ROWB;
                const float4 v0 = *(const float4*)(ra + (((2 * co) ^ sw) << 4));
                const float4 v1 = *(const float4*)(ra + (((2 * co + 1) ^ sw) << 4));
                acc8[0] = fmaf(w, v0.x, acc8[0]);
                acc8[1] = fmaf(w, v0.y, acc8[1]);
                acc8[2] = fmaf(w, v0.z, acc8[2]);
                acc8[3] = fmaf(w, v0.w, acc8[3]);
                acc8[4] = fmaf(w, v1.x, acc8[4]);
                acc8[5] = fmaf(w, v1.y, acc8[5]);
                acc8[6] = fmaf(w, v1.z, acc8[6]);
                acc8[7] = fmaf(w, v1.w, acc8[7]);
            }
        }
        asm volatile("s_waitcnt vmcnt(0)");  // tile k+1 DMA complete
        __syncthreads();  // #3: buf[pb] free; buf[pb^1] staged
        pb ^= 1;
    }

    if (lane == 0) sInv[wv] = (s_run > 0.0f) ? 1.0f / s_run : 0.0f;

    // ---- cross-wave reduce of quarter partials (alias sBuf; DMA drained) ----
    float* red = (float*)sBuf;  // 256 threads x 8 f32 = 8 KB
    *(float4*)&red[t * 8] = make_float4(acc8[0], acc8[1], acc8[2], acc8[3]);
    *(float4*)&red[t * 8 + 4] = make_float4(acc8[4], acc8[5], acc8[6], acc8[7]);
    __syncthreads();
    if (t < 64) {
        const float inv = sInv[t & 3];
        float* dst = &gWacc[(size_t)b * 512 + (t & 3) * F + (t >> 2) * 8];
        #pragma unroll
        for (int j = 0; j < 8; ++j) {
            const float s = red[t * 8 + j] + red[(t + 64) * 8 + j] +
                            red[(t + 128) * 8 + j] + red[(t + 192) * 8 + j];
            dst[j] = s * inv;
        }
    }
}

// K4: out[b] = silu(Wacc[b] @ Wp + bp). 8 crystals per block; Wp streamed
// coalesced from L2 once per block (Wacc LDS-staged, reused 8x).
__global__ __launch_bounds__(256) void proj_kernel(
    const float* __restrict__ gWacc, const float* __restrict__ Wp,
    const float* __restrict__ bp, float* __restrict__ out, int B) {
    __shared__ float sW[8 * 512];   // 16 KB
    __shared__ float sP[256 * 8];   // 8 KB
    const int t = threadIdx.x;
    const int c0 = blockIdx.x * 8;
    for (int q = t; q < 8 * 512; q += 256) {
        const int cr = c0 + (q >> 9);
        sW[q] = (cr < B) ? gWacc[(size_t)cr * 512 + (q & 511)] : 0.0f;
    }
    __syncthreads();
    const int f = t & 127, half = t >> 7;
    float acc[8] = {};
    const float* wp = Wp + (size_t)(half * 256) * F + f;
    for (int k = 0; k < 256; ++k) {
        const float wpv = wp[(size_t)k * F];  // lanes coalesced over f
        const int ks = half * 256 + k;        // wave-uniform -> LDS broadcast
        #pragma unroll
        for (int g = 0; g < 8; ++g) acc[g] = fmaf(sW[g * 512 + ks], wpv, acc[g]);
    }
    #pragma unroll
    for (int g = 0; g < 8; ++g) sP[t * 8 + g] = acc[g];
    __syncthreads();
    if (t < 128) {
        const float bpf = bp[t];
        #pragma unroll
        for (int g = 0; g < 8; ++g) {
            const int cr = c0 + g;
            if (cr < B)
                out[(size_t)cr * F + t] = silu_f(sP[t * 8 + g] + sP[(t + 128) * 8 + g] + bpf);
        }
    }
}

extern "C" void kernel_launch(void* const* d_in, const int* in_sizes, int n_in,
                              void* d_out, int out_size, void* d_ws, size_t ws_size,
                              hipStream_t stream) {
    const float* atom_fea = (const float*)d_in[0];
    const int* seg = (const int*)d_in[1];
    const float* W1 = (const float*)d_in[3];
    const float* b1 = (const float*)d_in[4];
    const float* W2 = (const float*)d_in[5];
    const float* b2 = (const float*)d_in[6];
    const float* Wp = (const float*)d_in[7];
    const float* bp = (const float*)d_in[8];
    float* out = (float*)d_out;

    const int N = in_sizes[0] / F;
    const int B = out_size / F;

    // ws layout: starts[B+1] | Wacc[B*512]
    char* ws = (char*)d_ws;
    int* starts = (int*)ws;
    size_t off = (((size_t)(B + 1) * sizeof(int)) + 255) & ~(size_t)255;
    float* gWacc = (float*)(ws + off);

    seg_starts_kernel<<<(N + 255) / 256, 256, 0, stream>>>(seg, starts, N, B);
    fused6_kernel<<<B, 256, 0, stream>>>(atom_fea, starts, W1, b1, W2, b2, gWacc);
    proj_kernel<<<(B + 7) / 8, 256, 0, stream>>>(gWacc, Wp, bp, out, B);
}

// Round 10
// 78.080 us; speedup vs baseline: 2.9166x; 1.0439x over previous
//
#include <hip/hip_runtime.h>
#include <math.h>

#define F 128
#define HID 32
#define NH 4
#define TILE 64
#define ROWB 512  // bytes per fp32 row (128 * 4)

typedef __attribute__((ext_vector_type(8))) short bf16x8;
typedef __attribute__((ext_vector_type(4))) float f32x4;

__device__ __forceinline__ float silu_f(float x) {
    return x / (1.0f + __expf(-x));
}

__device__ __forceinline__ uint f2bf(float f) {  // RNE float->bf16 (one-time W1 prep)
    union { float f; uint u; } v; v.f = f;
    uint r = v.u + 0x7fffu + ((v.u >> 16) & 1u);
    return r >> 16;
}

__device__ __forceinline__ uint cvtpk_bf16(float lo, float hi) {  // HW RNE pack
    uint r;
    asm("v_cvt_pk_bf16_f32 %0, %1, %2" : "=v"(r) : "v"(lo), "v"(hi));
    return r;
}

__device__ __forceinline__ void gload_lds16(const void* g, void* l) {
    // async 16B global->LDS; LDS dest is wave-uniform base + lane*16
    __builtin_amdgcn_global_load_lds(
        (const __attribute__((address_space(1))) void*)g,
        (__attribute__((address_space(3))) void*)l, 16, 0, 0);
}

// Scatter segment boundaries: starts[b] = first atom index with seg_id >= b.
__global__ void seg_starts_kernel(const int* __restrict__ seg, int* __restrict__ starts,
                                  int N, int B) {
    int i = blockIdx.x * blockDim.x + threadIdx.x;
    if (i >= N) return;
    int id = seg[i];
    if (i == 0) {
        for (int b = 0; b <= id; ++b) starts[b] = 0;
    } else {
        int prev = seg[i - 1];
        for (int b = prev + 1; b <= id; ++b) starts[b] = i;
    }
    if (i == N - 1) {
        for (int b = id + 1; b <= B; ++b) starts[b] = N;
    }
}

// One block (4 waves) per crystal. Per 64-atom tile (2 barriers, 3 blocks/CU):
//   B: MFMA MLP reads fp32 stage; bf16 frags ALSO stored to sBf tile -> sTL
//   bar1  (stage reads + sBf writes + sTL visible)
//   issue async DMA of tile k+1 into the (now free) single fp32 stage buffer
//   D: online softmax, wave wv = head wv (r stays in-register)
//   C: weighted accumulate from sBf, wave = head, lane = (atom-quad, feat-oct)
//   vmcnt(0); bar2
// Epilogue: 2x shfl_xor per acc + direct coalesced gWacc store (no LDS).
__global__ __launch_bounds__(256, 3) void fused7_kernel(
    const float* __restrict__ atom_fea, const int* __restrict__ starts,
    const float* __restrict__ W1, const float* __restrict__ b1,
    const float* __restrict__ W2, const float* __restrict__ b2,
    float* __restrict__ gWacc) {
    __shared__ float sStage[TILE * F];   // 32 KB fp32, 16B-chunk XOR swizzle (^ row&7)
    __shared__ ushort sBf[TILE * F];     // 16 KB bf16, 16B-chunk XOR swizzle (^ row&15)
    __shared__ float sTL[TILE * 5];      // logits [atom][head], stride 5
    __shared__ float sTW[NH * 65];       // exp weights [head][atom]

    const int t = threadIdx.x;
    const int b = blockIdx.x;
    const int start = starts[b];
    const int end = starts[b + 1];
    const int wv = t >> 6;    // wave: MFMA atom-group, softmax head, accum head
    const int lane = t & 63;
    const int lg = lane >> 4;
    const int l15 = lane & 15;
    const int p4 = lane >> 4;   // phase-C atom-quad offset (0..3)
    const int q8 = lane & 15;   // phase-C feat-oct (feats 8*q8..8*q8+8)

    // per-thread DMA slot constants: slot q holds LDS chunk (r, q&31),
    // sourced from global chunk (q&31)^(r&7) of row r (inverse swizzle)
    int roff[8], coff[8];
    #pragma unroll
    for (int i = 0; i < 8; ++i) {
        const int q = i * 256 + t;
        roff[i] = q >> 5;
        coff[i] = ((q & 31) ^ (roff[i] & 7)) << 4;
    }

    // ---- one-time register preloads (layout verified R6: absmax 9.8e-4) ----
    bf16x8 w1f[2][4];  // A-frags of W1T: [h-tile][k-step]; lane: h'=l15, k'=lg*8+j
    #pragma unroll
    for (int m0 = 0; m0 < 2; ++m0)
        #pragma unroll
        for (int kk = 0; kk < 4; ++kk) {
            bf16x8 fr;
            #pragma unroll
            for (int j = 0; j < 8; ++j)
                fr[j] = (short)f2bf(W1[(kk * 32 + lg * 8 + j) * HID + m0 * 16 + l15]);
            w1f[m0][kk] = fr;
        }
    float b1r[8], w2r[8][4];
    #pragma unroll
    for (int m0 = 0; m0 < 2; ++m0)
        #pragma unroll
        for (int r = 0; r < 4; ++r) {
            const int h = m0 * 16 + lg * 4 + r;
            b1r[m0 * 4 + r] = b1[h];
            #pragma unroll
            for (int j = 0; j < 4; ++j) w2r[m0 * 4 + r][j] = W2[h * NH + j];
        }
    const float b2r0 = b2[0], b2r1 = b2[1], b2r2 = b2[2], b2r3 = b2[3];

    float m_run = -INFINITY, s_run = 0.0f;
    float acc8[8] = {0, 0, 0, 0, 0, 0, 0, 0};  // head wv, feats 8*q8..+8, own atom-quads

    const int nt = (end > start) ? (end - start + TILE - 1) / TILE : 0;
    const char* gbase = (const char*)atom_fea;

    // ---- prologue: DMA tile 0 ----
    if (nt > 0) {
        #pragma unroll
        for (int i = 0; i < 8; ++i) {
            int a = start + roff[i]; a = (a < end) ? a : end - 1;  // clamp rows
            gload_lds16(gbase + (size_t)a * ROWB + coff[i],
                        (char*)sStage + i * 4096 + wv * 1024);
        }
    }
    asm volatile("s_waitcnt vmcnt(0)");
    __syncthreads();

    for (int ti = 0; ti < nt; ++ti) {
        const int base = start + ti * TILE;
        const int T = min(TILE, end - base);
        const bool has_next = (ti + 1 < nt);  // block-uniform

        // ---- B: MFMA MLP, wave wv owns atoms 16wv..16wv+15; frags -> sBf ----
        {
            f32x4 acc0, acc1;
            #pragma unroll
            for (int r = 0; r < 4; ++r) { acc0[r] = b1r[r]; acc1[r] = b1r[4 + r]; }
            const int row = wv * 16 + l15;
            const char* rb = (const char*)sStage + row * ROWB;
            const int rs = row & 7;
            #pragma unroll
            for (int kk = 0; kk < 4; ++kk) {
                const int c0 = kk * 8 + lg * 2;
                const float4 va = *(const float4*)(rb + ((c0 ^ rs) << 4));
                const float4 vb = *(const float4*)(rb + (((c0 + 1) ^ rs) << 4));
                union { bf16x8 v; uint u[4]; } fr;
                fr.u[0] = cvtpk_bf16(va.x, va.y);
                fr.u[1] = cvtpk_bf16(va.z, va.w);
                fr.u[2] = cvtpk_bf16(vb.x, vb.y);
                fr.u[3] = cvtpk_bf16(vb.z, vb.w);
                // store frag (feats (kk*4+lg)*8 .. +8 of atom `row`) to bf16 tile
                *(bf16x8*)&sBf[row * F + (((kk * 4 + lg) ^ (row & 15)) << 3)] = fr.v;
                acc0 = __builtin_amdgcn_mfma_f32_16x16x32_bf16(w1f[0][kk], fr.v, acc0, 0, 0, 0);
                acc1 = __builtin_amdgcn_mfma_f32_16x16x32_bf16(w1f[1][kk], fr.v, acc1, 0, 0, 0);
            }
            float p0 = 0, p1 = 0, p2 = 0, p3 = 0;
            #pragma unroll
            for (int r = 0; r < 4; ++r) {
                const float s0 = silu_f(acc0[r]);
                const float s1 = silu_f(acc1[r]);
                p0 = fmaf(s0, w2r[r][0], fmaf(s1, w2r[4 + r][0], p0));
                p1 = fmaf(s0, w2r[r][1], fmaf(s1, w2r[4 + r][1], p1));
                p2 = fmaf(s0, w2r[r][2], fmaf(s1, w2r[4 + r][2], p2));
                p3 = fmaf(s0, w2r[r][3], fmaf(s1, w2r[4 + r][3], p3));
            }
            p0 += __shfl_xor(p0, 16); p0 += __shfl_xor(p0, 32);
            p1 += __shfl_xor(p1, 16); p1 += __shfl_xor(p1, 32);
            p2 += __shfl_xor(p2, 16); p2 += __shfl_xor(p2, 32);
            p3 += __shfl_xor(p3, 16); p3 += __shfl_xor(p3, 32);
            if (lane < 16) {
                float* d = &sTL[(wv * 16 + lane) * 5];
                d[0] = p0 + b2r0; d[1] = p1 + b2r1; d[2] = p2 + b2r2; d[3] = p3 + b2r3;
            }
        }
        __syncthreads();  // bar1: stage reads, sBf writes, sTL all done/visible

        // ---- issue async DMA of tile k+1 into the (now free) stage buffer ----
        if (has_next) {
            const int nbase = base + TILE;
            #pragma unroll
            for (int i = 0; i < 8; ++i) {
                int a = nbase + roff[i]; a = (a < end) ? a : end - 1;
                gload_lds16(gbase + (size_t)a * ROWB + coff[i],
                            (char*)sStage + i * 4096 + wv * 1024);
            }
        }

        // ---- D: online softmax, wave wv = head wv, lane = atom ----
        float r_tile;
        {
            const float v = (lane < T) ? sTL[lane * 5 + wv] : -INFINITY;
            float mt = v;
            #pragma unroll
            for (int d = 1; d < 64; d <<= 1) mt = fmaxf(mt, __shfl_xor(mt, d));
            const float m_new = fmaxf(m_run, mt);
            r_tile = __expf(m_run - m_new);  // first tile: exp(-inf)=0
            const float e = (lane < T) ? __expf(v - m_new) : 0.0f;
            sTW[wv * 65 + lane] = e;  // own-wave region; same-wave read below
            float se = e;
            #pragma unroll
            for (int d = 1; d < 64; d <<= 1) se += __shfl_xor(se, d);
            s_run = fmaf(s_run, r_tile, se);
            m_run = m_new;
        }

        // ---- C: weighted accumulate from sBf; wave = head wv,
        //         lane = (atom-quad p4, feat-oct q8) ----
        {
            #pragma unroll
            for (int i = 0; i < 8; ++i) acc8[i] *= r_tile;
            #pragma unroll 4
            for (int i = 0; i < 16; ++i) {
                const int a = i * 4 + p4;
                const float w = sTW[wv * 65 + a];
                const uint4 d = *(const uint4*)&sBf[a * F + ((q8 ^ (a & 15)) << 3)];
                acc8[0] = fmaf(w, __uint_as_float(d.x << 16), acc8[0]);
                acc8[1] = fmaf(w, __uint_as_float(d.x & 0xffff0000u), acc8[1]);
                acc8[2] = fmaf(w, __uint_as_float(d.y << 16), acc8[2]);
                acc8[3] = fmaf(w, __uint_as_float(d.y & 0xffff0000u), acc8[3]);
                acc8[4] = fmaf(w, __uint_as_float(d.z << 16), acc8[4]);
                acc8[5] = fmaf(w, __uint_as_float(d.z & 0xffff0000u), acc8[5]);
                acc8[6] = fmaf(w, __uint_as_float(d.w << 16), acc8[6]);
                acc8[7] = fmaf(w, __uint_as_float(d.w & 0xffff0000u), acc8[7]);
            }
        }
        asm volatile("s_waitcnt vmcnt(0)");  // tile k+1 DMA landed
        __syncthreads();  // bar2: sBf/sTW reads done; stage ready for next B
    }

    // ---- epilogue: per-wave reduce over atom-quads + normalized store ----
    const float inv = (s_run > 0.0f) ? 1.0f / s_run : 0.0f;
    #pragma unroll
    for (int j = 0; j < 8; ++j) {
        acc8[j] += __shfl_xor(acc8[j], 16);
        acc8[j] += __shfl_xor(acc8[j], 32);
    }
    if (lane < 16) {
        float* dst = &gWacc[(size_t)b * 512 + wv * F + lane * 8];
        *(float4*)dst = make_float4(acc8[0] * inv, acc8[1] * inv, acc8[2] * inv, acc8[3] * inv);
        *(float4*)(dst + 4) = make_float4(acc8[4] * inv, acc8[5] * inv, acc8[6] * inv, acc8[7] * inv);
    }
}

// K4: out[b] = silu(Wacc[b] @ Wp + bp). 8 crystals per block; Wp streamed
// coalesced from L2 once per block (Wacc LDS-staged, reused 8x).
__global__ __launch_bounds__(256) void proj_kernel(
    const float* __restrict__ gWacc, const float* __restrict__ Wp,
    const float* __restrict__ bp, float* __restrict__ out, int B) {
    __shared__ float sW[8 * 512];   // 16 KB
    __shared__ float sP[256 * 8];   // 8 KB
    const int t = threadIdx.x;
    const int c0 = blockIdx.x * 8;
    for (int q = t; q < 8 * 512; q += 256) {
        const int cr = c0 + (q >> 9);
        sW[q] = (cr < B) ? gWacc[(size_t)cr * 512 + (q & 511)] : 0.0f;
    }
    __syncthreads();
    const int f = t & 127, half = t >> 7;
    float acc[8] = {};
    const float* wp = Wp + (size_t)(half * 256) * F + f;
    for (int k = 0; k < 256; ++k) {
        const float wpv = wp[(size_t)k * F];  // lanes coalesced over f
        const int ks = half * 256 + k;        // wave-uniform -> LDS broadcast
        #pragma unroll
        for (int g = 0; g < 8; ++g) acc[g] = fmaf(sW[g * 512 + ks], wpv, acc[g]);
    }
    #pragma unroll
    for (int g = 0; g < 8; ++g) sP[t * 8 + g] = acc[g];
    __syncthreads();
    if (t < 128) {
        const float bpf = bp[t];
        #pragma unroll
        for (int g = 0; g < 8; ++g) {
            const int cr = c0 + g;
            if (cr < B)
                out[(size_t)cr * F + t] = silu_f(sP[t * 8 + g] + sP[(t + 128) * 8 + g] + bpf);
        }
    }
}

extern "C" void kernel_launch(void* const* d_in, const int* in_sizes, int n_in,
                              void* d_out, int out_size, void* d_ws, size_t ws_size,
                              hipStream_t stream) {
    const float* atom_fea = (const float*)d_in[0];
    const int* seg = (const int*)d_in[1];
    const float* W1 = (const float*)d_in[3];
    const float* b1 = (const float*)d_in[4];
    const float* W2 = (const float*)d_in[5];
    const float* b2 = (const float*)d_in[6];
    const float* Wp = (const float*)d_in[7];
    const float* bp = (const float*)d_in[8];
    float* out = (float*)d_out;

    const int N = in_sizes[0] / F;
    const int B = out_size / F;

    // ws layout: starts[B+1] | Wacc[B*512]
    char* ws = (char*)d_ws;
    int* starts = (int*)ws;
    size_t off = (((size_t)(B + 1) * sizeof(int)) + 255) & ~(size_t)255;
    float* gWacc = (float*)(ws + off);

    seg_starts_kernel<<<(N + 255) / 256, 256, 0, stream>>>(seg, starts, N, B);
    fused7_kernel<<<B, 256, 0, stream>>>(atom_fea, starts, W1, b1, W2, b2, gWacc);
    proj_kernel<<<(B + 7) / 8, 256, 0, stream>>>(gWacc, Wp, bp, out, B);
}

// Round 11
// 75.829 us; speedup vs baseline: 3.0032x; 1.0297x over previous
//
#include <hip/hip_runtime.h>
#include <math.h>

#define F 128
#define HID 32
#define NH 4
#define TILE 32
#define ROWB 512  // bytes per fp32 row (128 * 4)

typedef __attribute__((ext_vector_type(8))) short bf16x8;
typedef __attribute__((ext_vector_type(4))) float f32x4;

__device__ __forceinline__ float silu_f(float x) {
    return x / (1.0f + __expf(-x));
}

__device__ __forceinline__ uint f2bf(float f) {  // RNE float->bf16 (one-time W1 prep)
    union { float f; uint u; } v; v.f = f;
    uint r = v.u + 0x7fffu + ((v.u >> 16) & 1u);
    return r >> 16;
}

__device__ __forceinline__ uint cvtpk_bf16(float lo, float hi) {  // HW RNE pack
    uint r;
    asm("v_cvt_pk_bf16_f32 %0, %1, %2" : "=v"(r) : "v"(lo), "v"(hi));
    return r;
}

__device__ __forceinline__ void gload_lds16(const void* g, void* l) {
    // async 16B global->LDS; LDS dest is wave-uniform base + lane*16
    __builtin_amdgcn_global_load_lds(
        (const __attribute__((address_space(1))) void*)g,
        (__attribute__((address_space(3))) void*)l, 16, 0, 0);
}

// Scatter segment boundaries: starts[b] = first atom index with seg_id >= b.
__global__ void seg_starts_kernel(const int* __restrict__ seg, int* __restrict__ starts,
                                  int N, int B) {
    int i = blockIdx.x * blockDim.x + threadIdx.x;
    if (i >= N) return;
    int id = seg[i];
    if (i == 0) {
        for (int b = 0; b <= id; ++b) starts[b] = 0;
    } else {
        int prev = seg[i - 1];
        for (int b = prev + 1; b <= id; ++b) starts[b] = i;
    }
    if (i == N - 1) {
        for (int b = id + 1; b <= B; ++b) starts[b] = N;
    }
}

// One block (4 waves) per crystal, 32-atom tiles, DOUBLE-buffered fp32 stage.
// Per tile: issue DMA(k+1)->buf[pb^1] at TOP (in flight the whole tile);
//   B: MFMA MLP on buf[pb]; wave = (atom-group ag, hid-half mh); partials->sP
//   bar1 = lgkmcnt(0) + raw s_barrier (NO vmcnt drain -> DMA stays in flight)
//   D: online softmax (halves summed from sP), wave wv = head wv
//   C: fp32 weighted accumulate from buf[pb]; lane = (atom-off lane&3, oct lane>>2)
//   __syncthreads() (drains vmcnt -> DMA(k+1) landed)
__global__ __launch_bounds__(256, 4) void fused8_kernel(
    const float* __restrict__ atom_fea, const int* __restrict__ starts,
    const float* __restrict__ W1, const float* __restrict__ b1,
    const float* __restrict__ W2, const float* __restrict__ b2,
    float* __restrict__ gWacc) {
    __shared__ float sStage[2][TILE * F];  // 2 x 16 KB, 16B-chunk XOR swizzle (^ row&7)
    __shared__ float sP[2 * TILE * 5];     // partial logits [half][atom][head], stride 5
    __shared__ float sTW[NH * 65];         // exp weights [head][atom]

    const int t = threadIdx.x;
    const int b = blockIdx.x;
    const int start = starts[b];
    const int end = starts[b + 1];
    const int wv = t >> 6;
    const int lane = t & 63;
    const int lg = lane >> 4;
    const int l15 = lane & 15;
    const int ag = wv & 1;        // MFMA atom-group (atoms 16ag..16ag+15)
    const int mh = wv >> 1;       // MFMA hid-half (hids 16mh..16mh+15)
    const int ca = lane & 3;      // phase-C atom offset within quad
    const int co = (lane >> 2) & 15;  // phase-C feat-oct (feats 8co..8co+7)

    // per-thread DMA slots: slot q holds LDS chunk (r, q&31) from global chunk
    // (q&31)^(r&7) of row r (inverse swizzle; read-side XOR recovers linear)
    int roff[4], coff[4];
    #pragma unroll
    for (int i = 0; i < 4; ++i) {
        const int q = i * 256 + t;
        roff[i] = q >> 5;
        coff[i] = ((q & 31) ^ (roff[i] & 7)) << 4;
    }

    // ---- one-time register preloads: only this wave's hid-half of W1T ----
    bf16x8 w1f[4];  // [k-step]; lane: h'=l15 (of half mh), k'=lg*8+j
    #pragma unroll
    for (int kk = 0; kk < 4; ++kk) {
        bf16x8 fr;
        #pragma unroll
        for (int j = 0; j < 8; ++j)
            fr[j] = (short)f2bf(W1[(kk * 32 + lg * 8 + j) * HID + mh * 16 + l15]);
        w1f[kk] = fr;
    }
    float b1r[4], w2r[4][4];
    #pragma unroll
    for (int r = 0; r < 4; ++r) {
        const int h = mh * 16 + lg * 4 + r;
        b1r[r] = b1[h];
        #pragma unroll
        for (int j = 0; j < 4; ++j) w2r[r][j] = W2[h * NH + j];
    }
    const float b2w = b2[wv];

    float m_run = -INFINITY, s_run = 0.0f;
    float acc8[8] = {0, 0, 0, 0, 0, 0, 0, 0};  // head wv, feats 8co..8co+7, atoms ca mod 4

    const int nt = (end > start) ? (end - start + TILE - 1) / TILE : 0;
    const char* gbase = (const char*)atom_fea;

    // ---- prologue: DMA tile 0 into buf0 ----
    if (nt > 0) {
        #pragma unroll
        for (int i = 0; i < 4; ++i) {
            int a = start + roff[i]; a = (a < end) ? a : end - 1;  // clamp rows
            gload_lds16(gbase + (size_t)a * ROWB + coff[i],
                        (char*)sStage[0] + i * 4096 + wv * 1024);
        }
    }
    __syncthreads();  // drains vmcnt(0): tile 0 staged

    int pb = 0;
    for (int ti = 0; ti < nt; ++ti) {
        const int base = start + ti * TILE;
        const int T = min(TILE, end - base);
        const char* bufc = (const char*)sStage[pb];
        const bool has_next = (ti + 1 < nt);  // block-uniform

        // ---- issue DMA(k+1) into alternate buffer: in flight the WHOLE tile ----
        if (has_next) {
            const int nbase = base + TILE;
            char* ldst = (char*)sStage[pb ^ 1];
            #pragma unroll
            for (int i = 0; i < 4; ++i) {
                int a = nbase + roff[i]; a = (a < end) ? a : end - 1;
                gload_lds16(gbase + (size_t)a * ROWB + coff[i],
                            ldst + i * 4096 + wv * 1024);
            }
        }

        // ---- B: MFMA MLP; wave (ag, mh): atoms 16ag..+16, hids 16mh..+16 ----
        {
            f32x4 acc;
            #pragma unroll
            for (int r = 0; r < 4; ++r) acc[r] = b1r[r];
            const int row = ag * 16 + l15;
            const char* rb = bufc + row * ROWB;
            const int rs = row & 7;
            #pragma unroll
            for (int kk = 0; kk < 4; ++kk) {
                const int c0 = kk * 8 + lg * 2;
                const float4 va = *(const float4*)(rb + ((c0 ^ rs) << 4));
                const float4 vb = *(const float4*)(rb + (((c0 + 1) ^ rs) << 4));
                union { bf16x8 v; uint u[4]; } fr;
                fr.u[0] = cvtpk_bf16(va.x, va.y);
                fr.u[1] = cvtpk_bf16(va.z, va.w);
                fr.u[2] = cvtpk_bf16(vb.x, vb.y);
                fr.u[3] = cvtpk_bf16(vb.z, vb.w);
                acc = __builtin_amdgcn_mfma_f32_16x16x32_bf16(w1f[kk], fr.v, acc, 0, 0, 0);
            }
            // silu + W2 partial over this wave's 16 hids (4 per lane, 4 lg groups)
            float p0 = 0, p1 = 0, p2 = 0, p3 = 0;
            #pragma unroll
            for (int r = 0; r < 4; ++r) {
                const float s = silu_f(acc[r]);
                p0 = fmaf(s, w2r[r][0], p0);
                p1 = fmaf(s, w2r[r][1], p1);
                p2 = fmaf(s, w2r[r][2], p2);
                p3 = fmaf(s, w2r[r][3], p3);
            }
            p0 += __shfl_xor(p0, 16); p0 += __shfl_xor(p0, 32);
            p1 += __shfl_xor(p1, 16); p1 += __shfl_xor(p1, 32);
            p2 += __shfl_xor(p2, 16); p2 += __shfl_xor(p2, 32);
            p3 += __shfl_xor(p3, 16); p3 += __shfl_xor(p3, 32);
            if (lane < 16) {
                float* d = &sP[(mh * TILE + ag * 16 + lane) * 5];
                d[0] = p0; d[1] = p1; d[2] = p2; d[3] = p3;
            }
        }
        // bar1: LDS-only fence (NO vmcnt drain -> DMA keeps streaming)
        asm volatile("s_waitcnt lgkmcnt(0)" ::: "memory");
        __builtin_amdgcn_s_barrier();

        // ---- D: online softmax; wave wv = head wv, lane = atom ----
        float r_tile;
        {
            const float v = (lane < T)
                ? sP[lane * 5 + wv] + sP[(TILE + lane) * 5 + wv] + b2w
                : -INFINITY;
            float mt = v;
            #pragma unroll
            for (int d = 1; d < 64; d <<= 1) mt = fmaxf(mt, __shfl_xor(mt, d));
            const float m_new = fmaxf(m_run, mt);
            r_tile = __expf(m_run - m_new);  // first tile: exp(-inf)=0
            const float e = (lane < T) ? __expf(v - m_new) : 0.0f;
            sTW[wv * 65 + lane] = e;  // own-wave region; same-wave read below
            float se = e;
            #pragma unroll
            for (int d = 1; d < 64; d <<= 1) se += __shfl_xor(se, d);
            s_run = fmaf(s_run, r_tile, se);
            m_run = m_new;
        }

        // ---- C: fp32 weighted accumulate; lane = (atom-off ca, oct co) ----
        {
            #pragma unroll
            for (int i = 0; i < 8; ++i) acc8[i] *= r_tile;
            #pragma unroll 4
            for (int i = 0; i < 8; ++i) {
                const int a = i * 4 + ca;
                const float w = sTW[wv * 65 + a];
                const int sw = a & 7;
                const char* ra = bufc + a * ROWB;
                const float4 v0 = *(const float4*)(ra + (((2 * co) ^ sw) << 4));
                const float4 v1 = *(const float4*)(ra + (((2 * co + 1) ^ sw) << 4));
                acc8[0] = fmaf(w, v0.x, acc8[0]);
                acc8[1] = fmaf(w, v0.y, acc8[1]);
                acc8[2] = fmaf(w, v0.z, acc8[2]);
                acc8[3] = fmaf(w, v0.w, acc8[3]);
                acc8[4] = fmaf(w, v1.x, acc8[4]);
                acc8[5] = fmaf(w, v1.y, acc8[5]);
                acc8[6] = fmaf(w, v1.z, acc8[6]);
                acc8[7] = fmaf(w, v1.w, acc8[7]);
            }
        }
        __syncthreads();  // drains vmcnt(0): DMA(k+1) landed; buf[pb] reads done
        pb ^= 1;
    }

    // ---- epilogue: reduce over atom-offset lanes (bits 0-1) + store ----
    const float inv = (s_run > 0.0f) ? 1.0f / s_run : 0.0f;
    #pragma unroll
    for (int j = 0; j < 8; ++j) {
        acc8[j] += __shfl_xor(acc8[j], 1);
        acc8[j] += __shfl_xor(acc8[j], 2);
    }
    if ((lane & 3) == 0) {
        float* dst = &gWacc[(size_t)b * 512 + wv * F + (lane >> 2) * 8];
        *(float4*)dst = make_float4(acc8[0] * inv, acc8[1] * inv, acc8[2] * inv, acc8[3] * inv);
        *(float4*)(dst + 4) = make_float4(acc8[4] * inv, acc8[5] * inv, acc8[6] * inv, acc8[7] * inv);
    }
}

// K4: out[b] = silu(Wacc[b] @ Wp + bp). 8 crystals per block; Wp streamed
// coalesced from L2 once per block (Wacc LDS-staged, reused 8x).
__global__ __launch_bounds__(256) void proj_kernel(
    const float* __restrict__ gWacc, const float* __restrict__ Wp,
    const float* __restrict__ bp, float* __restrict__ out, int B) {
    __shared__ float sW[8 * 512];   // 16 KB
    __shared__ float sP[256 * 8];   // 8 KB
    const int t = threadIdx.x;
    const int c0 = blockIdx.x * 8;
    for (int q = t; q < 8 * 512; q += 256) {
        const int cr = c0 + (q >> 9);
        sW[q] = (cr < B) ? gWacc[(size_t)cr * 512 + (q & 511)] : 0.0f;
    }
    __syncthreads();
    const int f = t & 127, half = t >> 7;
    float acc[8] = {};
    const float* wp = Wp + (size_t)(half * 256) * F + f;
    for (int k = 0; k < 256; ++k) {
        const float wpv = wp[(size_t)k * F];  // lanes coalesced over f
        const int ks = half * 256 + k;        // wave-uniform -> LDS broadcast
        #pragma unroll
        for (int g = 0; g < 8; ++g) acc[g] = fmaf(sW[g * 512 + ks], wpv, acc[g]);
    }
    #pragma unroll
    for (int g = 0; g < 8; ++g) sP[t * 8 + g] = acc[g];
    __syncthreads();
    if (t < 128) {
        const float bpf = bp[t];
        #pragma unroll
        for (int g = 0; g < 8; ++g) {
            const int cr = c0 + g;
            if (cr < B)
                out[(size_t)cr * F + t] = silu_f(sP[t * 8 + g] + sP[(t + 128) * 8 + g] + bpf);
        }
    }
}

extern "C" void kernel_launch(void* const* d_in, const int* in_sizes, int n_in,
                              void* d_out, int out_size, void* d_ws, size_t ws_size,
                              hipStream_t stream) {
    const float* atom_fea = (const float*)d_in[0];
    const int* seg = (const int*)d_in[1];
    const float* W1 = (const float*)d_in[3];
    const float* b1 = (const float*)d_in[4];
    const float* W2 = (const float*)d_in[5];
    const float* b2 = (const float*)d_in[6];
    const float* Wp = (const float*)d_in[7];
    const float* bp = (const float*)d_in[8];
    float* out = (float*)d_out;

    const int N = in_sizes[0] / F;
    const int B = out_size / F;

    // ws layout: starts[B+1] | Wacc[B*512]
    char* ws = (char*)d_ws;
    int* starts = (int*)ws;
    size_t off = (((size_t)(B + 1) * sizeof(int)) + 255) & ~(size_t)255;
    float* gWacc = (float*)(ws + off);

    seg_starts_kernel<<<(N + 255) / 256, 256, 0, stream>>>(seg, starts, N, B);
    fused8_kernel<<<B, 256, 0, stream>>>(atom_fea, starts, W1, b1, W2, b2, gWacc);
    proj_kernel<<<(B + 7) / 8, 256, 0, stream>>>(gWacc, Wp, bp, out, B);
}

// Round 12
// 64.723 us; speedup vs baseline: 3.5185x; 1.1716x over previous
//
#include <hip/hip_runtime.h>
#include <math.h>

#define F 128
#define HID 32
#define NH 4
#define TILE 32
#define ROWB 512  // bytes per fp32 row (128 * 4)
#define PJC 4     // crystals per proj block

typedef __attribute__((ext_vector_type(8))) short bf16x8;
typedef __attribute__((ext_vector_type(4))) float f32x4;

__device__ __forceinline__ float silu_f(float x) {
    return x / (1.0f + __expf(-x));
}

__device__ __forceinline__ uint f2bf(float f) {  // RNE float->bf16 (one-time W1 prep)
    union { float f; uint u; } v; v.f = f;
    uint r = v.u + 0x7fffu + ((v.u >> 16) & 1u);
    return r >> 16;
}

__device__ __forceinline__ uint cvtpk_bf16(float lo, float hi) {  // HW RNE pack
    uint r;
    asm("v_cvt_pk_bf16_f32 %0, %1, %2" : "=v"(r) : "v"(lo), "v"(hi));
    return r;
}

__device__ __forceinline__ void gload_lds16(const void* g, void* l) {
    // async 16B global->LDS; LDS dest is wave-uniform base + lane*16
    __builtin_amdgcn_global_load_lds(
        (const __attribute__((address_space(1))) void*)g,
        (__attribute__((address_space(3))) void*)l, 16, 0, 0);
}

// Scatter segment boundaries: starts[b] = first atom index with seg_id >= b.
__global__ void seg_starts_kernel(const int* __restrict__ seg, int* __restrict__ starts,
                                  int N, int B) {
    int i = blockIdx.x * blockDim.x + threadIdx.x;
    if (i >= N) return;
    int id = seg[i];
    if (i == 0) {
        for (int b = 0; b <= id; ++b) starts[b] = 0;
    } else {
        int prev = seg[i - 1];
        for (int b = prev + 1; b <= id; ++b) starts[b] = i;
    }
    if (i == N - 1) {
        for (int b = id + 1; b <= B; ++b) starts[b] = N;
    }
}

// One block (4 waves) per crystal, 32-atom tiles, double-buffered fp32 stage.
// Per tile: DMA(k+1) issued at top (in flight whole tile);
//   B: MFMA MLP on buf[pb]; wave = (atom-group ag, hid-half mh); partials->sP
//   bar1 = lgkmcnt(0) + raw s_barrier (no vmcnt drain)
//   D: DEFER-MAX softmax (T13): steady state = 1 exp + 1 ballot, no butterflies;
//      per-lane deferred denominator (one butterfly at block end)
//   C: fp32 weighted accumulate from buf[pb]
//   __syncthreads() (drains vmcnt -> DMA(k+1) landed)
__global__ __launch_bounds__(256, 4) void fused9_kernel(
    const float* __restrict__ atom_fea, const int* __restrict__ starts,
    const float* __restrict__ W1, const float* __restrict__ b1,
    const float* __restrict__ W2, const float* __restrict__ b2,
    float* __restrict__ gWacc) {
    __shared__ float sStage[2][TILE * F];  // 2 x 16 KB, 16B-chunk XOR swizzle (^ row&7)
    __shared__ float sP[2 * TILE * 5];     // partial logits [half][atom][head], stride 5
    __shared__ float sTW[NH * 65];         // exp weights [head][atom]

    const int t = threadIdx.x;
    const int b = blockIdx.x;
    const int start = starts[b];
    const int end = starts[b + 1];
    const int wv = t >> 6;
    const int lane = t & 63;
    const int lg = lane >> 4;
    const int l15 = lane & 15;
    const int ag = wv & 1;        // MFMA atom-group (atoms 16ag..16ag+15)
    const int mh = wv >> 1;       // MFMA hid-half (hids 16mh..16mh+15)
    const int ca = lane & 3;      // phase-C atom offset within quad
    const int co = (lane >> 2) & 15;  // phase-C feat-oct (feats 8co..8co+7)

    // per-thread DMA slots: slot q holds LDS chunk (r, q&31) from global chunk
    // (q&31)^(r&7) of row r (inverse swizzle; read-side XOR recovers linear)
    int roff[4], coff[4];
    #pragma unroll
    for (int i = 0; i < 4; ++i) {
        const int q = i * 256 + t;
        roff[i] = q >> 5;
        coff[i] = ((q & 31) ^ (roff[i] & 7)) << 4;
    }

    // ---- one-time register preloads: only this wave's hid-half of W1T ----
    bf16x8 w1f[4];  // [k-step]; lane: h'=l15 (of half mh), k'=lg*8+j
    #pragma unroll
    for (int kk = 0; kk < 4; ++kk) {
        bf16x8 fr;
        #pragma unroll
        for (int j = 0; j < 8; ++j)
            fr[j] = (short)f2bf(W1[(kk * 32 + lg * 8 + j) * HID + mh * 16 + l15]);
        w1f[kk] = fr;
    }
    float b1r[4], w2r[4][4];
    #pragma unroll
    for (int r = 0; r < 4; ++r) {
        const int h = mh * 16 + lg * 4 + r;
        b1r[r] = b1[h];
        #pragma unroll
        for (int j = 0; j < 4; ++j) w2r[r][j] = W2[h * NH + j];
    }
    const float b2w = b2[wv];

    float m_run = -INFINITY;
    float s_part = 0.0f;  // per-lane deferred denominator partial
    float acc8[8] = {0, 0, 0, 0, 0, 0, 0, 0};  // head wv, feats 8co..8co+7, atoms ca mod 4

    const int nt = (end > start) ? (end - start + TILE - 1) / TILE : 0;
    const char* gbase = (const char*)atom_fea;

    // ---- prologue: DMA tile 0 into buf0 ----
    if (nt > 0) {
        #pragma unroll
        for (int i = 0; i < 4; ++i) {
            int a = start + roff[i]; a = (a < end) ? a : end - 1;  // clamp rows
            gload_lds16(gbase + (size_t)a * ROWB + coff[i],
                        (char*)sStage[0] + i * 4096 + wv * 1024);
        }
    }
    __syncthreads();  // drains vmcnt(0): tile 0 staged

    int pb = 0;
    for (int ti = 0; ti < nt; ++ti) {
        const int base = start + ti * TILE;
        const int T = min(TILE, end - base);
        const char* bufc = (const char*)sStage[pb];
        const bool has_next = (ti + 1 < nt);  // block-uniform

        // ---- issue DMA(k+1) into alternate buffer: in flight the WHOLE tile ----
        if (has_next) {
            const int nbase = base + TILE;
            char* ldst = (char*)sStage[pb ^ 1];
            #pragma unroll
            for (int i = 0; i < 4; ++i) {
                int a = nbase + roff[i]; a = (a < end) ? a : end - 1;
                gload_lds16(gbase + (size_t)a * ROWB + coff[i],
                            ldst + i * 4096 + wv * 1024);
            }
        }

        // ---- B: MFMA MLP; wave (ag, mh): atoms 16ag..+16, hids 16mh..+16 ----
        {
            f32x4 acc;
            #pragma unroll
            for (int r = 0; r < 4; ++r) acc[r] = b1r[r];
            const int row = ag * 16 + l15;
            const char* rb = bufc + row * ROWB;
            const int rs = row & 7;
            #pragma unroll
            for (int kk = 0; kk < 4; ++kk) {
                const int c0 = kk * 8 + lg * 2;
                const float4 va = *(const float4*)(rb + ((c0 ^ rs) << 4));
                const float4 vb = *(const float4*)(rb + (((c0 + 1) ^ rs) << 4));
                union { bf16x8 v; uint u[4]; } fr;
                fr.u[0] = cvtpk_bf16(va.x, va.y);
                fr.u[1] = cvtpk_bf16(va.z, va.w);
                fr.u[2] = cvtpk_bf16(vb.x, vb.y);
                fr.u[3] = cvtpk_bf16(vb.z, vb.w);
                acc = __builtin_amdgcn_mfma_f32_16x16x32_bf16(w1f[kk], fr.v, acc, 0, 0, 0);
            }
            // silu + W2 partial over this wave's 16 hids (4 per lane, 4 lg groups)
            float p0 = 0, p1 = 0, p2 = 0, p3 = 0;
            #pragma unroll
            for (int r = 0; r < 4; ++r) {
                const float s = silu_f(acc[r]);
                p0 = fmaf(s, w2r[r][0], p0);
                p1 = fmaf(s, w2r[r][1], p1);
                p2 = fmaf(s, w2r[r][2], p2);
                p3 = fmaf(s, w2r[r][3], p3);
            }
            p0 += __shfl_xor(p0, 16); p0 += __shfl_xor(p0, 32);
            p1 += __shfl_xor(p1, 16); p1 += __shfl_xor(p1, 32);
            p2 += __shfl_xor(p2, 16); p2 += __shfl_xor(p2, 32);
            p3 += __shfl_xor(p3, 16); p3 += __shfl_xor(p3, 32);
            if (lane < 16) {
                float* d = &sP[(mh * TILE + ag * 16 + lane) * 5];
                d[0] = p0; d[1] = p1; d[2] = p2; d[3] = p3;
            }
        }
        // bar1: LDS-only fence (NO vmcnt drain -> DMA keeps streaming)
        asm volatile("s_waitcnt lgkmcnt(0)" ::: "memory");
        __builtin_amdgcn_s_barrier();

        // ---- D: defer-max online softmax (T13); wave wv = head wv, lane = atom ----
        {
            const float v = (lane < T)
                ? sP[lane * 5 + wv] + sP[(TILE + lane) * 5 + wv] + b2w
                : -INFINITY;
            if (__any(v > m_run + 8.0f)) {  // wave-uniform; rare after tile 0
                float mt = v;
                #pragma unroll
                for (int d = 1; d < 64; d <<= 1) mt = fmaxf(mt, __shfl_xor(mt, d));
                const float m_new = fmaxf(m_run, mt);
                const float r = __expf(m_run - m_new);  // first tile: exp(-inf)=0
                s_part *= r;
                #pragma unroll
                for (int j = 0; j < 8; ++j) acc8[j] *= r;
                m_run = m_new;
            }
            const float e = (lane < T) ? __expf(v - m_run) : 0.0f;  // bounded by e^8
            sTW[wv * 65 + lane] = e;  // own-wave region; same-wave read below
            s_part += e;
        }

        // ---- C: fp32 weighted accumulate; lane = (atom-off ca, oct co) ----
        {
            #pragma unroll 4
            for (int i = 0; i < 8; ++i) {
                const int a = i * 4 + ca;
                const float w = sTW[wv * 65 + a];
                const int sw = a & 7;
                const char* ra = bufc + a * ROWB;
                const float4 v0 = *(const float4*)(ra + (((2 * co) ^ sw) << 4));
                const float4 v1 = *(const float4*)(ra + (((2 * co + 1) ^ sw) << 4));
                acc8[0] = fmaf(w, v0.x, acc8[0]);
                acc8[1] = fmaf(w, v0.y, acc8[1]);
                acc8[2] = fmaf(w, v0.z, acc8[2]);
                acc8[3] = fmaf(w, v0.w, acc8[3]);
                acc8[4] = fmaf(w, v1.x, acc8[4]);
                acc8[5] = fmaf(w, v1.y, acc8[5]);
                acc8[6] = fmaf(w, v1.z, acc8[6]);
                acc8[7] = fmaf(w, v1.w, acc8[7]);
            }
        }
        __syncthreads();  // drains vmcnt(0): DMA(k+1) landed; buf[pb] reads done
        pb ^= 1;
    }

    // ---- epilogue: one denom butterfly + reduce over atom-offset lanes ----
    #pragma unroll
    for (int d = 1; d < 64; d <<= 1) s_part += __shfl_xor(s_part, d);
    const float inv = (s_part > 0.0f) ? 1.0f / s_part : 0.0f;
    #pragma unroll
    for (int j = 0; j < 8; ++j) {
        acc8[j] += __shfl_xor(acc8[j], 1);
        acc8[j] += __shfl_xor(acc8[j], 2);
    }
    if ((lane & 3) == 0) {
        float* dst = &gWacc[(size_t)b * 512 + wv * F + (lane >> 2) * 8];
        *(float4*)dst = make_float4(acc8[0] * inv, acc8[1] * inv, acc8[2] * inv, acc8[3] * inv);
        *(float4*)(dst + 4) = make_float4(acc8[4] * inv, acc8[5] * inv, acc8[6] * inv, acc8[7] * inv);
    }
}

// K4: out[b] = silu(Wacc[b] @ Wp + bp). PJC crystals per block (500 blocks ->
// 2/CU TLP); 8-deep Wp load batching (ILP vs serial per-k loads).
__global__ __launch_bounds__(256) void proj_kernel(
    const float* __restrict__ gWacc, const float* __restrict__ Wp,
    const float* __restrict__ bp, float* __restrict__ out, int B) {
    __shared__ float sW[PJC * 512];   // 8 KB
    __shared__ float sP[256 * PJC];   // 4 KB
    const int t = threadIdx.x;
    const int c0 = blockIdx.x * PJC;
    for (int q = t; q < PJC * 512; q += 256) {
        const int cr = c0 + (q >> 9);
        sW[q] = (cr < B) ? gWacc[(size_t)cr * 512 + (q & 511)] : 0.0f;
    }
    __syncthreads();
    const int f = t & 127, half = t >> 7;
    float acc[PJC] = {};
    const float* wp = Wp + (size_t)(half * 256) * F + f;
    for (int k0 = 0; k0 < 256; k0 += 8) {
        float wpv[8];
        #pragma unroll
        for (int u = 0; u < 8; ++u) wpv[u] = wp[(size_t)(k0 + u) * F];
        #pragma unroll
        for (int u = 0; u < 8; ++u) {
            const int ks = half * 256 + k0 + u;  // wave-uniform -> LDS broadcast
            #pragma unroll
            for (int g = 0; g < PJC; ++g) acc[g] = fmaf(sW[g * 512 + ks], wpv[u], acc[g]);
        }
    }
    #pragma unroll
    for (int g = 0; g < PJC; ++g) sP[t * PJC + g] = acc[g];
    __syncthreads();
    if (t < 128) {
        const float bpf = bp[t];
        #pragma unroll
        for (int g = 0; g < PJC; ++g) {
            const int cr = c0 + g;
            if (cr < B)
                out[(size_t)cr * F + t] =
                    silu_f(sP[t * PJC + g] + sP[(t + 128) * PJC + g] + bpf);
        }
    }
}

extern "C" void kernel_launch(void* const* d_in, const int* in_sizes, int n_in,
                              void* d_out, int out_size, void* d_ws, size_t ws_size,
                              hipStream_t stream) {
    const float* atom_fea = (const float*)d_in[0];
    const int* seg = (const int*)d_in[1];
    const float* W1 = (const float*)d_in[3];
    const float* b1 = (const float*)d_in[4];
    const float* W2 = (const float*)d_in[5];
    const float* b2 = (const float*)d_in[6];
    const float* Wp = (const float*)d_in[7];
    const float* bp = (const float*)d_in[8];
    float* out = (float*)d_out;

    const int N = in_sizes[0] / F;
    const int B = out_size / F;

    // ws layout: starts[B+1] | Wacc[B*512]
    char* ws = (char*)d_ws;
    int* starts = (int*)ws;
    size_t off = (((size_t)(B + 1) * sizeof(int)) + 255) & ~(size_t)255;
    float* gWacc = (float*)(ws + off);

    seg_starts_kernel<<<(N + 255) / 256, 256, 0, stream>>>(seg, starts, N, B);
    fused9_kernel<<<B, 256, 0, stream>>>(atom_fea, starts, W1, b1, W2, b2, gWacc);
    proj_kernel<<<(B + PJC - 1) / PJC, 256, 0, stream>>>(gWacc, Wp, bp, out, B);
}